// Round 7
// baseline (248.928 us; speedup 1.0000x reference)
//
#include <hip/hip_runtime.h>
#include <math.h>

#define CHUNK 8192
#define BSH 8            // bucket shift: 256 nodes per bucket
#define BNODES 256
#define RAWCAP 9216      // LDS edge capacity per bucket (avg 8192, sigma ~90 -> +11 sigma)
#define MAXCELL 512      // max chunks supported (E <= 4.19M)

// Workspace layout (4-byte units):
//   dinv  : N            rsqrt(1+deg)
//   ptrS  : N+1          CSR row starts (ptrS[N] = E)
//   tot   : nb           per-bucket edge totals
//   base  : nb+1         exclusive bucket bases (base[nb] = E)
//   off   : (nb+1)*NBLK  ushort per-(bucket,chunk) exclusive offsets
//   csr   : E            source nodes grouped by destination
//   tempU : max(E,32N)   binned packed edges; after k_build aliased by fp16
//                        feature tables h0h (16N halves = 8N ints) + h1h (8N ints)
//   g     : 16G          pooled graph accumulator

__global__ void k_init(int* tot, float* g, int nb, int G16) {
    int i = blockIdx.x * blockDim.x + threadIdx.x;
    if (i < nb)  tot[i] = 0;
    if (i < G16) g[i]   = 0.0f;
}

// Phase 1: bin this block's 8192-edge chunk by destination bucket.
// All scattered writes staged in LDS; temp written back as full coalesced lines.
__global__ __launch_bounds__(512) void k_bin(
                      const int* __restrict__ row, const int* __restrict__ col,
                      int* __restrict__ temp, unsigned short* __restrict__ off,
                      int* __restrict__ tot, int E, int NBLK, int nb) {
    __shared__ int cnt[512];
    __shared__ int cur[512];
    __shared__ int sc[512];
    __shared__ int stage[CHUNK];
    int blk = blockIdx.x;
    int start = blk * CHUNK;
    int cs = E - start; if (cs > CHUNK) cs = CHUNK;
    int t = threadIdx.x;     // 512 threads
    cnt[t] = 0;
    __syncthreads();
    for (int i = t; i < cs; i += 512) atomicAdd(&cnt[col[start + i] >> BSH], 1);
    __syncthreads();
    int c = cnt[t];
    sc[t] = c;
    __syncthreads();
    for (int o = 1; o < 512; o <<= 1) {
        int x = (t >= o) ? sc[t - o] : 0;
        __syncthreads();
        sc[t] += x;
        __syncthreads();
    }
    int excl = sc[t] - c;
    if (t < nb) {
        off[t * NBLK + blk] = (unsigned short)excl;
        if (c) atomicAdd(&tot[t], c);
    }
    if (t == 0) off[nb * NBLK + blk] = (unsigned short)cs;
    cur[t] = excl;
    __syncthreads();
    for (int i = t; i < cs; i += 512) {
        int cc = col[start + i];
        int rr = row[start + i];
        int p = atomicAdd(&cur[cc >> BSH], 1);
        stage[p] = (rr << BSH) | (cc & (BNODES - 1));
    }
    __syncthreads();
    for (int i = t; i < cs; i += 512) temp[start + i] = stage[i];
}

// exclusive scan of bucket totals -> base (carry loop); sentinels.
__global__ void k_base(const int* __restrict__ tot, int* __restrict__ base,
                       int* __restrict__ ptrS, int E, int nb, int N) {
    __shared__ int s[512];
    __shared__ int carry;
    int t = threadIdx.x;
    if (t == 0) carry = 0;
    __syncthreads();
    for (int b0 = 0; b0 < nb; b0 += 512) {
        int i = b0 + t;
        int v = (i < nb) ? tot[i] : 0;
        s[t] = v;
        __syncthreads();
        for (int o = 1; o < 512; o <<= 1) {
            int x = (t >= o) ? s[t - o] : 0;
            __syncthreads();
            s[t] += x;
            __syncthreads();
        }
        if (i < nb) base[i] = s[t] - v + carry;
        __syncthreads();
        if (t == 0) carry += s[511];
        __syncthreads();
    }
    if (t == 0) { base[nb] = E; ptrS[N] = E; }
}

// Phase 2: one block per 256-node bucket.
//  - wave-shuffle scans (few barriers)
//  - load+histogram fused in one pass over temp into LDS raw[]
//  - scatter writes csr DIRECTLY (block-exclusive ~33KB window stays L2-hot,
//    written back once) -- no stage[], no writeback pass
__global__ __launch_bounds__(512) void k_build(
                        const int* __restrict__ temp, const unsigned short* __restrict__ off,
                        const int* __restrict__ base, int* __restrict__ ptrS,
                        float* __restrict__ dinv, int* __restrict__ csr,
                        int NBLK, int N) {
    __shared__ int cnt[BNODES];
    __shared__ int cur[BNODES];
    __shared__ int cellstart[MAXCELL];
    __shared__ int wsum[8];
    __shared__ int raw[RAWCAP];
    int b = blockIdx.x;
    int t = threadIdx.x;     // 512 threads = 8 waves
    int wid = t >> 6, lane = t & 63;
    if (t < BNODES) cnt[t] = 0;
    // cell lengths + exclusive scan via wave shuffles (2 barriers)
    int len0 = 0;
    if (t < NBLK) len0 = (int)off[(b + 1) * NBLK + t] - (int)off[b * NBLK + t];
    int v = len0;
    for (int o = 1; o < 64; o <<= 1) {
        int u = __shfl_up(v, o, 64);
        if (lane >= o) v += u;
    }
    if (lane == 63) wsum[wid] = v;
    __syncthreads();
    int wb = 0;
    for (int i = 0; i < wid; ++i) wb += wsum[i];
    cellstart[t] = v - len0 + wb;   // exclusive
    __syncthreads();
    // Phase A: wave-per-cell coalesced load into raw[], histogram fused
    for (int cell = wid; cell < NBLK; cell += 8) {
        int s0 = off[b * NBLK + cell];
        int s1 = off[(b + 1) * NBLK + cell];
        int len = s1 - s0;
        int rb = cellstart[cell];
        const int* src = temp + cell * CHUNK + s0;
        for (int j = lane; j < len; j += 64) {
            int e = src[j];
            atomicAdd(&cnt[e & (BNODES - 1)], 1);
            int idx = rb + j;
            if (idx < RAWCAP) raw[idx] = e;
        }
    }
    __syncthreads();
    // per-node exclusive scan (256 lanes = waves 0..3) via wave shuffles
    int c = 0, sincl = 0;
    if (t < BNODES) {
        c = cnt[t];
        sincl = c;
        for (int o = 1; o < 64; o <<= 1) {
            int u = __shfl_up(sincl, o, 64);
            if (lane >= o) sincl += u;
        }
        if (lane == 63) wsum[wid] = sincl;
    }
    __syncthreads();
    int bb = base[b];
    int total = base[b + 1] - bb;
    if (t < BNODES) {
        int wb2 = 0;
        for (int i = 0; i < wid; ++i) wb2 += wsum[i];
        int gstart = bb + sincl - c + wb2;
        int node = (b << BSH) + t;
        if (node < N) {
            ptrS[node] = gstart;
            dinv[node] = rsqrtf(1.0f + (float)c);
        }
        cur[t] = gstart;
    }
    __syncthreads();
    // Phase C: scatter from LDS raw -> csr directly (L2-hot exclusive window)
    int cap = total > RAWCAP ? RAWCAP : total;
    for (int i = t; i < cap; i += 512) {
        int e = raw[i];
        int p = atomicAdd(&cur[e & (BNODES - 1)], 1);
        csr[p] = e >> BSH;
    }
    if (total > RAWCAP) {                  // statistically unreachable spill
        for (int cell = wid; cell < NBLK; cell += 8) {
            int s0 = off[b * NBLK + cell];
            int s1 = off[(b + 1) * NBLK + cell];
            int len = s1 - s0;
            int rb = cellstart[cell];
            const int* src = temp + cell * CHUNK + s0;
            for (int j = lane; j < len; j += 64) {
                if (rb + j >= RAWCAP) {
                    int e = src[j];
                    int p = atomicAdd(&cur[e & (BNODES - 1)], 1);
                    csr[p] = e >> BSH;
                }
            }
        }
    }
}

// h0h[v][k] = fp16( dinv[v] * (x @ W1)[v][k] )   (premultiplied, fp16 table)
__global__ void k_xw1(const float* __restrict__ x, const float* __restrict__ W1,
                      const float* __restrict__ dinv, _Float16* __restrict__ h0h, int N) {
    int t = blockIdx.x * blockDim.x + threadIdx.x;
    if (t >= N * 16) return;
    int v = t >> 4, k = t & 15;
    float x0 = x[v * 3 + 0], x1 = x[v * 3 + 1], x2 = x[v * 3 + 2];
    h0h[t] = (_Float16)(dinv[v] * (x0 * W1[k] + x1 * W1[16 + k] + x2 * W1[32 + k]));
}

// layer 1 gather over fp16 table (32B/row, L2-resident) + relu + W2 via shfl.
// Accumulation in f32. Writes h1h = fp16( dinv[v] * (h1 @ W2) ).
__global__ void k_gather1(const int* __restrict__ ptrS, const int* __restrict__ csr,
                          const float* __restrict__ dinv, const _Float16* __restrict__ h0h,
                          const float* __restrict__ W2, const float* __restrict__ b1,
                          _Float16* __restrict__ h1h, int N) {
    __shared__ float sW[256];
    sW[threadIdx.x] = W2[threadIdx.x];
    __syncthreads();
    int t = blockIdx.x * blockDim.x + threadIdx.x;
    int v = t >> 4, k = t & 15;
    if (v < N) {
        int s = ptrS[v], e = ptrS[v + 1];
        float a0 = 0.0f, a1 = 0.0f, a2 = 0.0f, a3 = 0.0f;
        int i = s;
        for (; i + 3 < e; i += 4) {
            int r0 = csr[i], r1 = csr[i + 1], r2 = csr[i + 2], r3 = csr[i + 3];
            a0 += (float)h0h[r0 * 16 + k];
            a1 += (float)h0h[r1 * 16 + k];
            a2 += (float)h0h[r2 * 16 + k];
            a3 += (float)h0h[r3 * 16 + k];
        }
        for (; i < e; ++i) a0 += (float)h0h[csr[i] * 16 + k];
        float d = dinv[v];
        float h = fmaxf(d * ((a0 + a1) + (a2 + a3) + (float)h0h[v * 16 + k]) + b1[k], 0.0f);
        float o = 0.0f;
#pragma unroll
        for (int j = 0; j < 16; ++j) o += __shfl(h, j, 16) * sW[j * 16 + k];
        h1h[v * 16 + k] = (_Float16)(d * o);
    }
}

// layer 2 gather over fp16 table + bias + pool with wave-level pre-reduction.
__global__ void k_gather2(const int* __restrict__ ptrS, const int* __restrict__ csr,
                          const float* __restrict__ dinv, const _Float16* __restrict__ h1h,
                          const float* __restrict__ b2, const int* __restrict__ batch,
                          float* __restrict__ g, int N) {
    int t = blockIdx.x * blockDim.x + threadIdx.x;
    int v = t >> 4, k = t & 15;
    bool valid = (v < N);
    float val = 0.0f;
    int bg = 0;
    if (valid) {
        int s = ptrS[v], e = ptrS[v + 1];
        float a0 = 0.0f, a1 = 0.0f, a2 = 0.0f, a3 = 0.0f;
        int i = s;
        for (; i + 3 < e; i += 4) {
            int r0 = csr[i], r1 = csr[i + 1], r2 = csr[i + 2], r3 = csr[i + 3];
            a0 += (float)h1h[r0 * 16 + k];
            a1 += (float)h1h[r1 * 16 + k];
            a2 += (float)h1h[r2 * 16 + k];
            a3 += (float)h1h[r3 * 16 + k];
        }
        for (; i < e; ++i) a0 += (float)h1h[csr[i] * 16 + k];
        float d = dinv[v];
        val = d * ((a0 + a1) + (a2 + a3) + (float)h1h[v * 16 + k]) + b2[k];
        bg = batch[v];
    }
    int lane = threadIdx.x & 63;
    int bg0 = __shfl(bg, lane & 15, 64);
    bool uni = __all(valid && (bg == bg0));
    if (uni) {
        val += __shfl_xor(val, 16, 64);
        val += __shfl_xor(val, 32, 64);
        if (lane < 16) atomicAdd(&g[bg * 16 + k], val);
    } else if (valid) {
        atomicAdd(&g[bg * 16 + k], val);
    }
}

// logits = g @ Wl + bl (16x7), then log_softmax over 7. One thread per graph.
__global__ void k_head(const float* __restrict__ g, const float* __restrict__ Wl,
                       const float* __restrict__ bl, float* __restrict__ out, int G) {
    int gi = blockIdx.x * blockDim.x + threadIdx.x;
    if (gi >= G) return;
    float gv[16];
#pragma unroll
    for (int k = 0; k < 16; ++k) gv[k] = g[gi * 16 + k];
    float lo[7];
    float mx = -1e30f;
#pragma unroll
    for (int j = 0; j < 7; ++j) {
        float a = bl[j];
#pragma unroll
        for (int k = 0; k < 16; ++k) a += gv[k] * Wl[k * 7 + j];
        lo[j] = a;
        mx = fmaxf(mx, a);
    }
    float s = 0.0f;
#pragma unroll
    for (int j = 0; j < 7; ++j) s += expf(lo[j] - mx);
    float lse = mx + logf(s);
#pragma unroll
    for (int j = 0; j < 7; ++j) out[gi * 7 + j] = lo[j] - lse;
}

extern "C" void kernel_launch(void* const* d_in, const int* in_sizes, int n_in,
                              void* d_out, int out_size, void* d_ws, size_t ws_size,
                              hipStream_t stream) {
    const float* x    = (const float*)d_in[0];
    const int*   ei   = (const int*)d_in[1];   // [2, E]: row = ei[0:E), col = ei[E:2E)
    const int*   batch = (const int*)d_in[3];
    const float* W1 = (const float*)d_in[4];
    const float* b1 = (const float*)d_in[5];
    const float* W2 = (const float*)d_in[6];
    const float* b2 = (const float*)d_in[7];
    const float* Wl = (const float*)d_in[8];
    const float* bl = (const float*)d_in[9];
    float* out = (float*)d_out;

    const int N = in_sizes[0] / 3;
    const int E = in_sizes[1] / 2;
    const int G = out_size / 7;

    const int* row = ei;
    const int* col = ei + E;

    const int NBLK = (E + CHUNK - 1) / CHUNK;   // must be <= MAXCELL (E <= 4.19M)
    const int nb   = (N + BNODES - 1) >> BSH;

    int* w = (int*)d_ws;
    float* dinv = (float*)w;            w += N;
    int*   ptrS = w;                    w += N + 1;
    int*   tot  = w;                    w += nb;
    int*   base = w;                    w += nb + 1;
    unsigned short* off = (unsigned short*)w;
    w += ((nb + 1) * NBLK + 1) / 2;     // ushort table, rounded up to int units
    int*   csr  = w;                    w += E;
    int tempsz = E > 32 * N ? E : 32 * N;
    int*   temp = w;                    w += tempsz;
    // fp16 feature tables alias temp (dead after k_build)
    _Float16* h0h = (_Float16*)temp;             // 16N halves = 8N ints
    _Float16* h1h = (_Float16*)(temp + 8 * N);   // 16N halves = 8N ints
    float* g    = (float*)w;            w += 16 * G;

    const int TB = 256;
    const int n16 = N * 16;
    const int G16 = G * 16;
    const int initn = (G16 > nb) ? G16 : nb;

    k_init<<<(initn + TB - 1) / TB, TB, 0, stream>>>(tot, g, nb, G16);
    k_bin<<<NBLK, 512, 0, stream>>>(row, col, temp, off, tot, E, NBLK, nb);
    k_base<<<1, 512, 0, stream>>>(tot, base, ptrS, E, nb, N);
    k_build<<<nb, 512, 0, stream>>>(temp, off, base, ptrS, dinv, csr, NBLK, N);
    k_xw1<<<(n16 + TB - 1) / TB, TB, 0, stream>>>(x, W1, dinv, h0h, N);
    k_gather1<<<(n16 + TB - 1) / TB, TB, 0, stream>>>(ptrS, csr, dinv, h0h, W2, b1, h1h, N);
    k_gather2<<<(n16 + TB - 1) / TB, TB, 0, stream>>>(ptrS, csr, dinv, h1h, b2, batch, g, N);
    k_head<<<(G + TB - 1) / TB, TB, 0, stream>>>(g, Wl, bl, out, G);
}

// Round 8
// 213.136 us; speedup vs baseline: 1.1679x; 1.1679x over previous
//
#include <hip/hip_runtime.h>
#include <math.h>

#define CHUNK 8192
#define BSH 8            // bucket shift: 256 nodes per bucket
#define BNODES 256
#define RAWCAP 9216      // LDS edge capacity per bucket (avg 8192, sigma ~90 -> +11 sigma)
#define MAXCELL 512      // max chunks supported (E <= 4.19M)

// Workspace layout (4-byte units):
//   dinv  : N            rsqrt(1+deg)
//   ptrS  : N+1          CSR row starts (ptrS[N] = E)
//   tot   : nb           per-bucket edge totals
//   base  : nb+1         exclusive bucket bases (base[nb] = E)
//   off   : (nb+1)*NBLK  ushort per-(bucket,chunk) exclusive offsets
//   csr   : E            source nodes grouped by destination
//   tempU : max(E,32N)   binned packed edges; after k_build aliased by fp16
//                        feature tables h0h (16N halves = 8N ints) + h1h (8N ints)
//   g     : 16G          pooled graph accumulator

__global__ void k_init(int* tot, float* g, int nb, int G16) {
    int i = blockIdx.x * blockDim.x + threadIdx.x;
    if (i < nb)  tot[i] = 0;
    if (i < G16) g[i]   = 0.0f;
}

// Phase 1: bin this block's 8192-edge chunk by destination bucket.
// All scattered writes staged in LDS; temp written back as full coalesced lines.
__global__ __launch_bounds__(512) void k_bin(
                      const int* __restrict__ row, const int* __restrict__ col,
                      int* __restrict__ temp, unsigned short* __restrict__ off,
                      int* __restrict__ tot, int E, int NBLK, int nb) {
    __shared__ int cnt[512];
    __shared__ int cur[512];
    __shared__ int sc[512];
    __shared__ int stage[CHUNK];
    int blk = blockIdx.x;
    int start = blk * CHUNK;
    int cs = E - start; if (cs > CHUNK) cs = CHUNK;
    int t = threadIdx.x;     // 512 threads
    cnt[t] = 0;
    __syncthreads();
    for (int i = t; i < cs; i += 512) atomicAdd(&cnt[col[start + i] >> BSH], 1);
    __syncthreads();
    int c = cnt[t];
    sc[t] = c;
    __syncthreads();
    for (int o = 1; o < 512; o <<= 1) {
        int x = (t >= o) ? sc[t - o] : 0;
        __syncthreads();
        sc[t] += x;
        __syncthreads();
    }
    int excl = sc[t] - c;
    if (t < nb) {
        off[t * NBLK + blk] = (unsigned short)excl;
        if (c) atomicAdd(&tot[t], c);
    }
    if (t == 0) off[nb * NBLK + blk] = (unsigned short)cs;
    cur[t] = excl;
    __syncthreads();
    for (int i = t; i < cs; i += 512) {
        int cc = col[start + i];
        int rr = row[start + i];
        int p = atomicAdd(&cur[cc >> BSH], 1);
        stage[p] = (rr << BSH) | (cc & (BNODES - 1));
    }
    __syncthreads();
    for (int i = t; i < cs; i += 512) temp[start + i] = stage[i];
}

// exclusive scan of bucket totals -> base (carry loop); sentinels.
__global__ void k_base(const int* __restrict__ tot, int* __restrict__ base,
                       int* __restrict__ ptrS, int E, int nb, int N) {
    __shared__ int s[512];
    __shared__ int carry;
    int t = threadIdx.x;
    if (t == 0) carry = 0;
    __syncthreads();
    for (int b0 = 0; b0 < nb; b0 += 512) {
        int i = b0 + t;
        int v = (i < nb) ? tot[i] : 0;
        s[t] = v;
        __syncthreads();
        for (int o = 1; o < 512; o <<= 1) {
            int x = (t >= o) ? s[t - o] : 0;
            __syncthreads();
            s[t] += x;
            __syncthreads();
        }
        if (i < nb) base[i] = s[t] - v + carry;
        __syncthreads();
        if (t == 0) carry += s[511];
        __syncthreads();
    }
    if (t == 0) { base[nb] = E; ptrS[N] = E; }
}

// Phase 2: one block per 256-node bucket, 1024 threads (16 waves).
// Grid packs in ONE round: 391 blocks at 2 blocks/CU (LDS 79.9KB, 32 waves/CU).
//  - off row + cellstarts cached in LDS (no dependent global chain in load loop)
//  - 16-lane cell groups load temp coalesced; histogram fused into load
//  - wave-shuffle scans; scatter into LDS stage; coalesced writeback
__global__ __launch_bounds__(1024) void k_build(
                        const int* __restrict__ temp, const unsigned short* __restrict__ off,
                        const int* __restrict__ base, int* __restrict__ ptrS,
                        float* __restrict__ dinv, int* __restrict__ csr,
                        int NBLK, int N) {
    __shared__ int cnt[BNODES];
    __shared__ int cur[BNODES];
    __shared__ int cellstart[MAXCELL];
    __shared__ int soff[MAXCELL];
    __shared__ int wsum[16];
    __shared__ int raw[RAWCAP];
    __shared__ int stage[RAWCAP];
    int b = blockIdx.x;
    int t = threadIdx.x;     // 1024 threads = 16 waves
    int wid = t >> 6, lane = t & 63;
    if (t < BNODES) cnt[t] = 0;
    // phase 0: cache off row, cell lengths, exclusive scan (waves 0..7)
    int len0 = 0;
    if (t < MAXCELL) {
        int s0v = 0;
        if (t < NBLK) {
            s0v = (int)off[b * NBLK + t];
            len0 = (int)off[(b + 1) * NBLK + t] - s0v;
        }
        soff[t] = s0v;
        int v = len0;
        for (int o = 1; o < 64; o <<= 1) {
            int u = __shfl_up(v, o, 64);
            if (lane >= o) v += u;
        }
        if (lane == 63) wsum[wid] = v;
        cellstart[t] = v - len0;   // within-wave exclusive; add wave base below
    }
    __syncthreads();
    if (t < MAXCELL) {
        int wb = 0;
        for (int i = 0; i < wid; ++i) wb += wsum[i];
        cellstart[t] += wb;
    }
    __syncthreads();
    int bb = base[b];
    int total = base[b + 1] - bb;
    // Phase A: 16-lane-group per cell, coalesced load into raw[], histogram fused
    int grp = t >> 4, gl = t & 15;     // 64 groups of 16 lanes
    for (int cell = grp; cell < NBLK; cell += 64) {
        int s0 = soff[cell];
        int rb = cellstart[cell];
        int len = ((cell + 1 < NBLK) ? cellstart[cell + 1] : total) - rb;
        const int* src = temp + cell * CHUNK + s0;
        for (int j = gl; j < len; j += 16) {
            int e = src[j];
            atomicAdd(&cnt[e & (BNODES - 1)], 1);
            int idx = rb + j;
            if (idx < RAWCAP) raw[idx] = e;
        }
    }
    __syncthreads();
    // Phase B: per-node exclusive scan (waves 0..3) via wave shuffles
    int c = 0, sincl = 0;
    if (t < BNODES) {
        c = cnt[t];
        sincl = c;
        for (int o = 1; o < 64; o <<= 1) {
            int u = __shfl_up(sincl, o, 64);
            if (lane >= o) sincl += u;
        }
        if (lane == 63) wsum[wid] = sincl;
    }
    __syncthreads();
    if (t < BNODES) {
        int wb2 = 0;
        for (int i = 0; i < wid; ++i) wb2 += wsum[i];
        int lstart = sincl - c + wb2;      // local start within bucket
        int node = (b << BSH) + t;
        if (node < N) {
            ptrS[node] = bb + lstart;
            dinv[node] = rsqrtf(1.0f + (float)c);
        }
        cur[t] = lstart;
    }
    __syncthreads();
    // Phase C: scatter LDS raw -> LDS stage (local positions)
    int cap = total > RAWCAP ? RAWCAP : total;
    for (int i = t; i < cap; i += 1024) {
        int e = raw[i];
        int p = atomicAdd(&cur[e & (BNODES - 1)], 1);
        int r = e >> BSH;
        if (p < RAWCAP) stage[p] = r;
        else            csr[bb + p] = r;   // statistically unreachable
    }
    if (total > RAWCAP) {                  // statistically unreachable spill
        for (int cell = grp; cell < NBLK; cell += 64) {
            int s0 = soff[cell];
            int rb = cellstart[cell];
            int len = ((cell + 1 < NBLK) ? cellstart[cell + 1] : total) - rb;
            const int* src = temp + cell * CHUNK + s0;
            for (int j = gl; j < len; j += 16) {
                if (rb + j >= RAWCAP) {
                    int e = src[j];
                    int p = atomicAdd(&cur[e & (BNODES - 1)], 1);
                    int r = e >> BSH;
                    if (p < RAWCAP) stage[p] = r;
                    else            csr[bb + p] = r;
                }
            }
        }
    }
    __syncthreads();
    // Phase D: coalesced writeback
    for (int i = t; i < cap; i += 1024) csr[bb + i] = stage[i];
}

// h0h[v][k] = fp16( dinv[v] * (x @ W1)[v][k] )   (premultiplied, fp16 table)
__global__ void k_xw1(const float* __restrict__ x, const float* __restrict__ W1,
                      const float* __restrict__ dinv, _Float16* __restrict__ h0h, int N) {
    int t = blockIdx.x * blockDim.x + threadIdx.x;
    if (t >= N * 16) return;
    int v = t >> 4, k = t & 15;
    float x0 = x[v * 3 + 0], x1 = x[v * 3 + 1], x2 = x[v * 3 + 2];
    h0h[t] = (_Float16)(dinv[v] * (x0 * W1[k] + x1 * W1[16 + k] + x2 * W1[32 + k]));
}

// layer 1 gather over fp16 table (32B/row, L2-resident) + relu + W2 via shfl.
// Accumulation in f32. Writes h1h = fp16( dinv[v] * (h1 @ W2) ).
__global__ void k_gather1(const int* __restrict__ ptrS, const int* __restrict__ csr,
                          const float* __restrict__ dinv, const _Float16* __restrict__ h0h,
                          const float* __restrict__ W2, const float* __restrict__ b1,
                          _Float16* __restrict__ h1h, int N) {
    __shared__ float sW[256];
    sW[threadIdx.x] = W2[threadIdx.x];
    __syncthreads();
    int t = blockIdx.x * blockDim.x + threadIdx.x;
    int v = t >> 4, k = t & 15;
    if (v < N) {
        int s = ptrS[v], e = ptrS[v + 1];
        float a0 = 0.0f, a1 = 0.0f, a2 = 0.0f, a3 = 0.0f;
        int i = s;
        for (; i + 3 < e; i += 4) {
            int r0 = csr[i], r1 = csr[i + 1], r2 = csr[i + 2], r3 = csr[i + 3];
            a0 += (float)h0h[r0 * 16 + k];
            a1 += (float)h0h[r1 * 16 + k];
            a2 += (float)h0h[r2 * 16 + k];
            a3 += (float)h0h[r3 * 16 + k];
        }
        for (; i < e; ++i) a0 += (float)h0h[csr[i] * 16 + k];
        float d = dinv[v];
        float h = fmaxf(d * ((a0 + a1) + (a2 + a3) + (float)h0h[v * 16 + k]) + b1[k], 0.0f);
        float o = 0.0f;
#pragma unroll
        for (int j = 0; j < 16; ++j) o += __shfl(h, j, 16) * sW[j * 16 + k];
        h1h[v * 16 + k] = (_Float16)(d * o);
    }
}

// layer 2 gather over fp16 table + bias + pool with wave-level pre-reduction.
__global__ void k_gather2(const int* __restrict__ ptrS, const int* __restrict__ csr,
                          const float* __restrict__ dinv, const _Float16* __restrict__ h1h,
                          const float* __restrict__ b2, const int* __restrict__ batch,
                          float* __restrict__ g, int N) {
    int t = blockIdx.x * blockDim.x + threadIdx.x;
    int v = t >> 4, k = t & 15;
    bool valid = (v < N);
    float val = 0.0f;
    int bg = 0;
    if (valid) {
        int s = ptrS[v], e = ptrS[v + 1];
        float a0 = 0.0f, a1 = 0.0f, a2 = 0.0f, a3 = 0.0f;
        int i = s;
        for (; i + 3 < e; i += 4) {
            int r0 = csr[i], r1 = csr[i + 1], r2 = csr[i + 2], r3 = csr[i + 3];
            a0 += (float)h1h[r0 * 16 + k];
            a1 += (float)h1h[r1 * 16 + k];
            a2 += (float)h1h[r2 * 16 + k];
            a3 += (float)h1h[r3 * 16 + k];
        }
        for (; i < e; ++i) a0 += (float)h1h[csr[i] * 16 + k];
        float d = dinv[v];
        val = d * ((a0 + a1) + (a2 + a3) + (float)h1h[v * 16 + k]) + b2[k];
        bg = batch[v];
    }
    int lane = threadIdx.x & 63;
    int bg0 = __shfl(bg, lane & 15, 64);
    bool uni = __all(valid && (bg == bg0));
    if (uni) {
        val += __shfl_xor(val, 16, 64);
        val += __shfl_xor(val, 32, 64);
        if (lane < 16) atomicAdd(&g[bg * 16 + k], val);
    } else if (valid) {
        atomicAdd(&g[bg * 16 + k], val);
    }
}

// logits = g @ Wl + bl (16x7), then log_softmax over 7. One thread per graph.
__global__ void k_head(const float* __restrict__ g, const float* __restrict__ Wl,
                       const float* __restrict__ bl, float* __restrict__ out, int G) {
    int gi = blockIdx.x * blockDim.x + threadIdx.x;
    if (gi >= G) return;
    float gv[16];
#pragma unroll
    for (int k = 0; k < 16; ++k) gv[k] = g[gi * 16 + k];
    float lo[7];
    float mx = -1e30f;
#pragma unroll
    for (int j = 0; j < 7; ++j) {
        float a = bl[j];
#pragma unroll
        for (int k = 0; k < 16; ++k) a += gv[k] * Wl[k * 7 + j];
        lo[j] = a;
        mx = fmaxf(mx, a);
    }
    float s = 0.0f;
#pragma unroll
    for (int j = 0; j < 7; ++j) s += expf(lo[j] - mx);
    float lse = mx + logf(s);
#pragma unroll
    for (int j = 0; j < 7; ++j) out[gi * 7 + j] = lo[j] - lse;
}

extern "C" void kernel_launch(void* const* d_in, const int* in_sizes, int n_in,
                              void* d_out, int out_size, void* d_ws, size_t ws_size,
                              hipStream_t stream) {
    const float* x    = (const float*)d_in[0];
    const int*   ei   = (const int*)d_in[1];   // [2, E]: row = ei[0:E), col = ei[E:2E)
    const int*   batch = (const int*)d_in[3];
    const float* W1 = (const float*)d_in[4];
    const float* b1 = (const float*)d_in[5];
    const float* W2 = (const float*)d_in[6];
    const float* b2 = (const float*)d_in[7];
    const float* Wl = (const float*)d_in[8];
    const float* bl = (const float*)d_in[9];
    float* out = (float*)d_out;

    const int N = in_sizes[0] / 3;
    const int E = in_sizes[1] / 2;
    const int G = out_size / 7;

    const int* row = ei;
    const int* col = ei + E;

    const int NBLK = (E + CHUNK - 1) / CHUNK;   // must be <= MAXCELL (E <= 4.19M)
    const int nb   = (N + BNODES - 1) >> BSH;

    int* w = (int*)d_ws;
    float* dinv = (float*)w;            w += N;
    int*   ptrS = w;                    w += N + 1;
    int*   tot  = w;                    w += nb;
    int*   base = w;                    w += nb + 1;
    unsigned short* off = (unsigned short*)w;
    w += ((nb + 1) * NBLK + 1) / 2;     // ushort table, rounded up to int units
    int*   csr  = w;                    w += E;
    int tempsz = E > 32 * N ? E : 32 * N;
    int*   temp = w;                    w += tempsz;
    // fp16 feature tables alias temp (dead after k_build)
    _Float16* h0h = (_Float16*)temp;             // 16N halves = 8N ints
    _Float16* h1h = (_Float16*)(temp + 8 * N);   // 16N halves = 8N ints
    float* g    = (float*)w;            w += 16 * G;

    const int TB = 256;
    const int n16 = N * 16;
    const int G16 = G * 16;
    const int initn = (G16 > nb) ? G16 : nb;

    k_init<<<(initn + TB - 1) / TB, TB, 0, stream>>>(tot, g, nb, G16);
    k_bin<<<NBLK, 512, 0, stream>>>(row, col, temp, off, tot, E, NBLK, nb);
    k_base<<<1, 512, 0, stream>>>(tot, base, ptrS, E, nb, N);
    k_build<<<nb, 1024, 0, stream>>>(temp, off, base, ptrS, dinv, csr, NBLK, N);
    k_xw1<<<(n16 + TB - 1) / TB, TB, 0, stream>>>(x, W1, dinv, h0h, N);
    k_gather1<<<(n16 + TB - 1) / TB, TB, 0, stream>>>(ptrS, csr, dinv, h0h, W2, b1, h1h, N);
    k_gather2<<<(n16 + TB - 1) / TB, TB, 0, stream>>>(ptrS, csr, dinv, h1h, b2, batch, g, N);
    k_head<<<(G + TB - 1) / TB, TB, 0, stream>>>(g, Wl, bl, out, G);
}

// Round 9
// 210.400 us; speedup vs baseline: 1.1831x; 1.0130x over previous
//
#include <hip/hip_runtime.h>
#include <math.h>

#define CHUNK 8192
#define BSH 8            // bucket shift: 256 nodes per bucket
#define BNODES 256
#define RAWCAP 9216      // LDS edge capacity per bucket (avg 8192, sigma ~90 -> +11 sigma)
#define MAXCELL 512      // max chunks supported (E <= 4.19M)

// Workspace layout (4-byte units):
//   dinv  : N            rsqrt(1+deg)
//   ptrS  : N+1          CSR row starts (ptrS[N] = E)
//   tot   : nb           per-bucket edge totals
//   base  : nb+1         exclusive bucket bases (base[nb] = E)
//   off   : (nb+1)*NBLK  ushort per-(bucket,chunk) exclusive offsets
//   csr   : E            source nodes grouped by destination
//   tempU : max(E,32N)   binned packed edges; after k_build aliased by packed-fp16
//                        feature tables h0u (8N u32) + h1u (8N u32)
//   g     : 16G          pooled graph accumulator

union H2 { unsigned int u; _Float16 h[2]; };

__global__ void k_init(int* tot, float* g, int nb, int G16) {
    int i = blockIdx.x * blockDim.x + threadIdx.x;
    if (i < nb)  tot[i] = 0;
    if (i < G16) g[i]   = 0.0f;
}

// Phase 1: bin this block's 8192-edge chunk by destination bucket.
// All scattered writes staged in LDS; temp written back as full coalesced lines.
__global__ __launch_bounds__(512) void k_bin(
                      const int* __restrict__ row, const int* __restrict__ col,
                      int* __restrict__ temp, unsigned short* __restrict__ off,
                      int* __restrict__ tot, int E, int NBLK, int nb) {
    __shared__ int cnt[512];
    __shared__ int cur[512];
    __shared__ int sc[512];
    __shared__ int stage[CHUNK];
    int blk = blockIdx.x;
    int start = blk * CHUNK;
    int cs = E - start; if (cs > CHUNK) cs = CHUNK;
    int t = threadIdx.x;     // 512 threads
    cnt[t] = 0;
    __syncthreads();
    for (int i = t; i < cs; i += 512) atomicAdd(&cnt[col[start + i] >> BSH], 1);
    __syncthreads();
    int c = cnt[t];
    sc[t] = c;
    __syncthreads();
    for (int o = 1; o < 512; o <<= 1) {
        int x = (t >= o) ? sc[t - o] : 0;
        __syncthreads();
        sc[t] += x;
        __syncthreads();
    }
    int excl = sc[t] - c;
    if (t < nb) {
        off[t * NBLK + blk] = (unsigned short)excl;
        if (c) atomicAdd(&tot[t], c);
    }
    if (t == 0) off[nb * NBLK + blk] = (unsigned short)cs;
    cur[t] = excl;
    __syncthreads();
    for (int i = t; i < cs; i += 512) {
        int cc = col[start + i];
        int rr = row[start + i];
        int p = atomicAdd(&cur[cc >> BSH], 1);
        stage[p] = (rr << BSH) | (cc & (BNODES - 1));
    }
    __syncthreads();
    for (int i = t; i < cs; i += 512) temp[start + i] = stage[i];
}

// exclusive scan of bucket totals -> base (carry loop); sentinels.
__global__ void k_base(const int* __restrict__ tot, int* __restrict__ base,
                       int* __restrict__ ptrS, int E, int nb, int N) {
    __shared__ int s[512];
    __shared__ int carry;
    int t = threadIdx.x;
    if (t == 0) carry = 0;
    __syncthreads();
    for (int b0 = 0; b0 < nb; b0 += 512) {
        int i = b0 + t;
        int v = (i < nb) ? tot[i] : 0;
        s[t] = v;
        __syncthreads();
        for (int o = 1; o < 512; o <<= 1) {
            int x = (t >= o) ? s[t - o] : 0;
            __syncthreads();
            s[t] += x;
            __syncthreads();
        }
        if (i < nb) base[i] = s[t] - v + carry;
        __syncthreads();
        if (t == 0) carry += s[511];
        __syncthreads();
    }
    if (t == 0) { base[nb] = E; ptrS[N] = E; }
}

// Phase 2: one block per 256-node bucket, 1024 threads (16 waves).
// Grid packs in ONE round: 391 blocks at 2 blocks/CU.
__global__ __launch_bounds__(1024) void k_build(
                        const int* __restrict__ temp, const unsigned short* __restrict__ off,
                        const int* __restrict__ base, int* __restrict__ ptrS,
                        float* __restrict__ dinv, int* __restrict__ csr,
                        int NBLK, int N) {
    __shared__ int cnt[BNODES];
    __shared__ int cur[BNODES];
    __shared__ int cellstart[MAXCELL];
    __shared__ int soff[MAXCELL];
    __shared__ int wsum[16];
    __shared__ int raw[RAWCAP];
    __shared__ int stage[RAWCAP];
    int b = blockIdx.x;
    int t = threadIdx.x;     // 1024 threads = 16 waves
    int wid = t >> 6, lane = t & 63;
    if (t < BNODES) cnt[t] = 0;
    int len0 = 0;
    if (t < MAXCELL) {
        int s0v = 0;
        if (t < NBLK) {
            s0v = (int)off[b * NBLK + t];
            len0 = (int)off[(b + 1) * NBLK + t] - s0v;
        }
        soff[t] = s0v;
        int v = len0;
        for (int o = 1; o < 64; o <<= 1) {
            int u = __shfl_up(v, o, 64);
            if (lane >= o) v += u;
        }
        if (lane == 63) wsum[wid] = v;
        cellstart[t] = v - len0;
    }
    __syncthreads();
    if (t < MAXCELL) {
        int wb = 0;
        for (int i = 0; i < wid; ++i) wb += wsum[i];
        cellstart[t] += wb;
    }
    __syncthreads();
    int bb = base[b];
    int total = base[b + 1] - bb;
    int grp = t >> 4, gl = t & 15;     // 64 groups of 16 lanes
    for (int cell = grp; cell < NBLK; cell += 64) {
        int s0 = soff[cell];
        int rb = cellstart[cell];
        int len = ((cell + 1 < NBLK) ? cellstart[cell + 1] : total) - rb;
        const int* src = temp + cell * CHUNK + s0;
        for (int j = gl; j < len; j += 16) {
            int e = src[j];
            atomicAdd(&cnt[e & (BNODES - 1)], 1);
            int idx = rb + j;
            if (idx < RAWCAP) raw[idx] = e;
        }
    }
    __syncthreads();
    int c = 0, sincl = 0;
    if (t < BNODES) {
        c = cnt[t];
        sincl = c;
        for (int o = 1; o < 64; o <<= 1) {
            int u = __shfl_up(sincl, o, 64);
            if (lane >= o) sincl += u;
        }
        if (lane == 63) wsum[wid] = sincl;
    }
    __syncthreads();
    if (t < BNODES) {
        int wb2 = 0;
        for (int i = 0; i < wid; ++i) wb2 += wsum[i];
        int lstart = sincl - c + wb2;
        int node = (b << BSH) + t;
        if (node < N) {
            ptrS[node] = bb + lstart;
            dinv[node] = rsqrtf(1.0f + (float)c);
        }
        cur[t] = lstart;
    }
    __syncthreads();
    int cap = total > RAWCAP ? RAWCAP : total;
    for (int i = t; i < cap; i += 1024) {
        int e = raw[i];
        int p = atomicAdd(&cur[e & (BNODES - 1)], 1);
        int r = e >> BSH;
        if (p < RAWCAP) stage[p] = r;
        else            csr[bb + p] = r;   // statistically unreachable
    }
    if (total > RAWCAP) {                  // statistically unreachable spill
        for (int cell = grp; cell < NBLK; cell += 64) {
            int s0 = soff[cell];
            int rb = cellstart[cell];
            int len = ((cell + 1 < NBLK) ? cellstart[cell + 1] : total) - rb;
            const int* src = temp + cell * CHUNK + s0;
            for (int j = gl; j < len; j += 16) {
                if (rb + j >= RAWCAP) {
                    int e = src[j];
                    int p = atomicAdd(&cur[e & (BNODES - 1)], 1);
                    int r = e >> BSH;
                    if (p < RAWCAP) stage[p] = r;
                    else            csr[bb + p] = r;
                }
            }
        }
    }
    __syncthreads();
    for (int i = t; i < cap; i += 1024) csr[bb + i] = stage[i];
}

// Packed table: h0u[v*8+k2] = two fp16 features (2*k2, 2*k2+1), premultiplied by dinv.
__global__ void k_xw1(const float* __restrict__ x, const float* __restrict__ W1,
                      const float* __restrict__ dinv, unsigned int* __restrict__ h0u, int N) {
    int t = blockIdx.x * blockDim.x + threadIdx.x;
    if (t >= N * 8) return;
    int v = t >> 3, k = (t & 7) * 2;
    float x0 = x[v * 3 + 0], x1 = x[v * 3 + 1], x2 = x[v * 3 + 2];
    float d = dinv[v];
    H2 p;
    p.h[0] = (_Float16)(d * (x0 * W1[k] + x1 * W1[16 + k] + x2 * W1[32 + k]));
    p.h[1] = (_Float16)(d * (x0 * W1[k + 1] + x1 * W1[16 + k + 1] + x2 * W1[32 + k + 1]));
    h0u[t] = p.u;
}

// Layer-1 gather: 8 lanes/node, packed-u32 rows. Per 8-edge window: ONE coalesced
// csr load (lane gl) + __shfl broadcast (DS pipe, no VMEM) + 8 u32 table loads
// servicing 8 nodes/wave. f32 accumulation; relu + W2 via 8-lane shfl; packed store.
__global__ void k_gather1(const int* __restrict__ ptrS, const int* __restrict__ csr,
                          const float* __restrict__ dinv, const unsigned int* __restrict__ h0u,
                          const float* __restrict__ W2, const float* __restrict__ b1,
                          unsigned int* __restrict__ h1u, int N) {
    __shared__ float sW[256];
    sW[threadIdx.x] = W2[threadIdx.x];
    __syncthreads();
    int t = blockIdx.x * blockDim.x + threadIdx.x;
    int v = t >> 3, gl = t & 7, k = gl * 2;
    if (v >= N) return;
    int s = ptrS[v], e = ptrS[v + 1];
    float al0 = 0.0f, ah0 = 0.0f, al1 = 0.0f, ah1 = 0.0f;
    int i = s;
    for (; i + 7 < e; i += 8) {
        int myr = __builtin_nontemporal_load(csr + i + gl);
#pragma unroll
        for (int q = 0; q < 8; ++q) {
            int r = __shfl(myr, q, 8);
            H2 p; p.u = h0u[r * 8 + gl];
            if (q & 1) { al1 += (float)p.h[0]; ah1 += (float)p.h[1]; }
            else       { al0 += (float)p.h[0]; ah0 += (float)p.h[1]; }
        }
    }
    if (i < e) {
        int rem = e - i;
        int myr = (gl < rem) ? __builtin_nontemporal_load(csr + i + gl) : 0;
        for (int q = 0; q < rem; ++q) {
            int r = __shfl(myr, q, 8);
            H2 p; p.u = h0u[r * 8 + gl];
            al0 += (float)p.h[0]; ah0 += (float)p.h[1];
        }
    }
    H2 selfp; selfp.u = h0u[v * 8 + gl];
    float d = dinv[v];
    float h_lo = fmaxf(d * (al0 + al1 + (float)selfp.h[0]) + b1[k], 0.0f);
    float h_hi = fmaxf(d * (ah0 + ah1 + (float)selfp.h[1]) + b1[k + 1], 0.0f);
    float o0 = 0.0f, o1 = 0.0f;
#pragma unroll
    for (int j = 0; j < 8; ++j) {
        float hl = __shfl(h_lo, j, 8);
        float hh = __shfl(h_hi, j, 8);
        o0 += hl * sW[(2 * j) * 16 + k]     + hh * sW[(2 * j + 1) * 16 + k];
        o1 += hl * sW[(2 * j) * 16 + k + 1] + hh * sW[(2 * j + 1) * 16 + k + 1];
    }
    H2 outp;
    outp.h[0] = (_Float16)(d * o0);
    outp.h[1] = (_Float16)(d * o1);
    __builtin_nontemporal_store(outp.u, h1u + v * 8 + gl);
}

// Layer-2 gather (same 8-lane structure) + bias + pool with wave pre-reduction
// (8 nodes/wave -> one pair of atomics per feature-pair when graph-uniform).
__global__ void k_gather2(const int* __restrict__ ptrS, const int* __restrict__ csr,
                          const float* __restrict__ dinv, const unsigned int* __restrict__ h1u,
                          const float* __restrict__ b2, const int* __restrict__ batch,
                          float* __restrict__ g, int N) {
    int t = blockIdx.x * blockDim.x + threadIdx.x;
    int v = t >> 3, gl = t & 7, k = gl * 2;
    bool valid = (v < N);
    float val0 = 0.0f, val1 = 0.0f;
    int bg = 0;
    if (valid) {
        int s = ptrS[v], e = ptrS[v + 1];
        float al0 = 0.0f, ah0 = 0.0f, al1 = 0.0f, ah1 = 0.0f;
        int i = s;
        for (; i + 7 < e; i += 8) {
            int myr = __builtin_nontemporal_load(csr + i + gl);
#pragma unroll
            for (int q = 0; q < 8; ++q) {
                int r = __shfl(myr, q, 8);
                H2 p; p.u = h1u[r * 8 + gl];
                if (q & 1) { al1 += (float)p.h[0]; ah1 += (float)p.h[1]; }
                else       { al0 += (float)p.h[0]; ah0 += (float)p.h[1]; }
            }
        }
        if (i < e) {
            int rem = e - i;
            int myr = (gl < rem) ? __builtin_nontemporal_load(csr + i + gl) : 0;
            for (int q = 0; q < rem; ++q) {
                int r = __shfl(myr, q, 8);
                H2 p; p.u = h1u[r * 8 + gl];
                al0 += (float)p.h[0]; ah0 += (float)p.h[1];
            }
        }
        H2 selfp; selfp.u = h1u[v * 8 + gl];
        float d = dinv[v];
        val0 = d * (al0 + al1 + (float)selfp.h[0]) + b2[k];
        val1 = d * (ah0 + ah1 + (float)selfp.h[1]) + b2[k + 1];
        bg = batch[v];
    }
    int lane = threadIdx.x & 63;
    int bg0 = __shfl(bg, lane & 7, 64);
    bool uni = __all(valid && (bg == bg0));
    if (uni) {
        val0 += __shfl_xor(val0, 8, 64);
        val0 += __shfl_xor(val0, 16, 64);
        val0 += __shfl_xor(val0, 32, 64);
        val1 += __shfl_xor(val1, 8, 64);
        val1 += __shfl_xor(val1, 16, 64);
        val1 += __shfl_xor(val1, 32, 64);
        if (lane < 8) {
            atomicAdd(&g[bg * 16 + k], val0);
            atomicAdd(&g[bg * 16 + k + 1], val1);
        }
    } else if (valid) {
        atomicAdd(&g[bg * 16 + k], val0);
        atomicAdd(&g[bg * 16 + k + 1], val1);
    }
}

// logits = g @ Wl + bl (16x7), then log_softmax over 7. One thread per graph.
__global__ void k_head(const float* __restrict__ g, const float* __restrict__ Wl,
                       const float* __restrict__ bl, float* __restrict__ out, int G) {
    int gi = blockIdx.x * blockDim.x + threadIdx.x;
    if (gi >= G) return;
    float gv[16];
#pragma unroll
    for (int k = 0; k < 16; ++k) gv[k] = g[gi * 16 + k];
    float lo[7];
    float mx = -1e30f;
#pragma unroll
    for (int j = 0; j < 7; ++j) {
        float a = bl[j];
#pragma unroll
        for (int k = 0; k < 16; ++k) a += gv[k] * Wl[k * 7 + j];
        lo[j] = a;
        mx = fmaxf(mx, a);
    }
    float s = 0.0f;
#pragma unroll
    for (int j = 0; j < 7; ++j) s += expf(lo[j] - mx);
    float lse = mx + logf(s);
#pragma unroll
    for (int j = 0; j < 7; ++j) out[gi * 7 + j] = lo[j] - lse;
}

extern "C" void kernel_launch(void* const* d_in, const int* in_sizes, int n_in,
                              void* d_out, int out_size, void* d_ws, size_t ws_size,
                              hipStream_t stream) {
    const float* x    = (const float*)d_in[0];
    const int*   ei   = (const int*)d_in[1];   // [2, E]: row = ei[0:E), col = ei[E:2E)
    const int*   batch = (const int*)d_in[3];
    const float* W1 = (const float*)d_in[4];
    const float* b1 = (const float*)d_in[5];
    const float* W2 = (const float*)d_in[6];
    const float* b2 = (const float*)d_in[7];
    const float* Wl = (const float*)d_in[8];
    const float* bl = (const float*)d_in[9];
    float* out = (float*)d_out;

    const int N = in_sizes[0] / 3;
    const int E = in_sizes[1] / 2;
    const int G = out_size / 7;

    const int* row = ei;
    const int* col = ei + E;

    const int NBLK = (E + CHUNK - 1) / CHUNK;   // must be <= MAXCELL (E <= 4.19M)
    const int nb   = (N + BNODES - 1) >> BSH;

    int* w = (int*)d_ws;
    float* dinv = (float*)w;            w += N;
    int*   ptrS = w;                    w += N + 1;
    int*   tot  = w;                    w += nb;
    int*   base = w;                    w += nb + 1;
    unsigned short* off = (unsigned short*)w;
    w += ((nb + 1) * NBLK + 1) / 2;     // ushort table, rounded up to int units
    int*   csr  = w;                    w += E;
    int tempsz = E > 32 * N ? E : 32 * N;
    int*   temp = w;                    w += tempsz;
    // packed-fp16 feature tables alias temp (dead after k_build)
    unsigned int* h0u = (unsigned int*)temp;        // 8N u32
    unsigned int* h1u = (unsigned int*)(temp + 8 * N);
    float* g    = (float*)w;            w += 16 * G;

    const int TB = 256;
    const int n8  = N * 8;
    const int G16 = G * 16;
    const int initn = (G16 > nb) ? G16 : nb;

    k_init<<<(initn + TB - 1) / TB, TB, 0, stream>>>(tot, g, nb, G16);
    k_bin<<<NBLK, 512, 0, stream>>>(row, col, temp, off, tot, E, NBLK, nb);
    k_base<<<1, 512, 0, stream>>>(tot, base, ptrS, E, nb, N);
    k_build<<<nb, 1024, 0, stream>>>(temp, off, base, ptrS, dinv, csr, NBLK, N);
    k_xw1<<<(n8 + TB - 1) / TB, TB, 0, stream>>>(x, W1, dinv, h0u, N);
    k_gather1<<<(n8 + TB - 1) / TB, TB, 0, stream>>>(ptrS, csr, dinv, h0u, W2, b1, h1u, N);
    k_gather2<<<(n8 + TB - 1) / TB, TB, 0, stream>>>(ptrS, csr, dinv, h1u, b2, batch, g, N);
    k_head<<<(G + TB - 1) / TB, TB, 0, stream>>>(g, Wl, bl, out, G);
}